// Round 7
// baseline (226.755 us; speedup 1.0000x reference)
//
#include <hip/hip_runtime.h>
#include <cmath>

// ConvLSTM, two-phase:
//   Phase 1: xg = conv_same(x[:, ::-1], Wx), one parallel kernel.
//            Direct global loads (x is L2/L3-resident; LDS staging measured
//            SLOWER in R6). Each thread: 2 output rows x 4 px x 8 chans,
//            5 input rows reused across the 2 rows. Explicit depth-1
//            register pipeline over c (load c+1 while computing c).
//   Phase 2: 16 sequential step kernels (h-conv + gates), ~BW-floor.
//
// x:  (B=8, T=16, C=16, H=128, W=128) f32
// Wx: (KH=4, KW=2, C=16, O=8) HWIO     idx = kh*256 + kw*128 + c*8 + o
// Wh: (KH=4, KW=2, F=2, O=8)
// out:(B, T, F=2, H, W) f32
// ws: xg (64 MiB, layout [t][b][o][h][w]) + c-state (1 MiB)

constexpr int B_ = 8;
constexpr int T_ = 16;
constexpr int C_ = 16;
constexpr int F_ = 2;
constexpr int O_ = 8;
constexpr int H_ = 128;
constexpr int W_ = 128;
constexpr int HW_ = H_ * W_;
constexpr int KH_ = 4;
constexpr int KW_ = 2;
constexpr int PX_ = 4;
constexpr int RY_ = 2;                 // output rows per thread
constexpr int NR_ = RY_ + KH_ - 1;     // 5 input rows per thread

typedef float fv4 __attribute__((ext_vector_type(4)));

__device__ __forceinline__ float hsig(float z) {
    return fminf(fmaxf(0.2f * z + 0.5f, 0.0f), 1.0f);
}

__device__ __forceinline__ float ftanh(float x) {
    float e = __expf(2.0f * x);
    return fmaf(-2.0f, 1.0f / (e + 1.0f), 1.0f);
}

// load 5 rows x 5 values of channel plane xc (base already at +ow4)
template<bool CHECK>
__device__ __forceinline__ void load_rows(
    const float* __restrict__ xc, int r0, bool cval, int co4,
    float xv[NR_][PX_ + 1])
{
    #pragma unroll
    for (int rr = 0; rr < NR_; ++rr) {
        int ih  = r0 - 1 + rr;               // pad_top = 1
        bool v  = true;
        int ihc = ih;
        if (CHECK) {
            v   = (unsigned)ih < (unsigned)H_;
            ihc = v ? ih : 0;
        }
        const float* r = xc + ihc * W_;
        fv4   a  = *reinterpret_cast<const fv4*>(r);
        float t4 = r[co4];                   // clamped addr, in-bounds
        xv[rr][0] = a.x;
        xv[rr][1] = a.y;
        xv[rr][2] = a.z;
        xv[rr][3] = a.w;
        xv[rr][4] = cval ? t4 : 0.0f;
        if (CHECK && !v) {
            #pragma unroll
            for (int p = 0; p < PX_ + 1; ++p) xv[rr][p] = 0.0f;
        }
    }
}

__device__ __forceinline__ void accum(
    const float* __restrict__ wc,            // Wx + c*O_
    const float xv[NR_][PX_ + 1],
    float acc[RY_][PX_][O_])
{
    #pragma unroll
    for (int kh = 0; kh < KH_; ++kh) {
        const float* wp = wc + kh * (KW_ * C_ * O_);
        #pragma unroll
        for (int o = 0; o < O_; ++o) {
            float w0 = wp[o];                // kw = 0 (uniform -> SGPR)
            float w1 = wp[C_ * O_ + o];      // kw = 1
            #pragma unroll
            for (int r = 0; r < RY_; ++r) {
                #pragma unroll
                for (int p = 0; p < PX_; ++p) {
                    acc[r][p][o] = fmaf(xv[kh + r][p],     w0, acc[r][p][o]);
                    acc[r][p][o] = fmaf(xv[kh + r][p + 1], w1, acc[r][p][o]);
                }
            }
        }
    }
}

template<bool CHECK>
__device__ __forceinline__ void conv_pipeline(
    const float* __restrict__ xs, const float* __restrict__ Wx,
    int r0, bool cval, int co4, float acc[RY_][PX_][O_], int ow4)
{
    float xv[NR_][PX_ + 1], xvn[NR_][PX_ + 1];
    load_rows<CHECK>(xs + ow4, r0, cval, co4, xv);
    #pragma unroll 1
    for (int c = 0; c < C_ - 1; ++c) {
        load_rows<CHECK>(xs + (c + 1) * HW_ + ow4, r0, cval, co4, xvn);
        accum(Wx + c * O_, xv, acc);
        #pragma unroll
        for (int rr = 0; rr < NR_; ++rr)
            #pragma unroll
            for (int p = 0; p < PX_ + 1; ++p) xv[rr][p] = xvn[rr][p];
    }
    accum(Wx + (C_ - 1) * O_, xv, acc);
}

// grid: 1024 blocks x 256 thr; block = 16-row slab of one (b,t) image;
// thread = 2 rows x 4 px, all 8 gate chans.
__global__ __launch_bounds__(256, 4) void xg_kernel(
    const float* __restrict__ x,
    const float* __restrict__ Wx,
    float* __restrict__ xg)
{
    // XCD-chunked swizzle (1024 % 8 == 0 -> bijective); one image's 8 slabs
    // stay inside one 128-chunk -> same XCD L2 for halo reuse.
    int wid = (blockIdx.x & 7) * 128 + (blockIdx.x >> 3);

    int bt   = wid >> 3;             // 8 blocks per (b,t)
    int slab = wid & 7;

    int tid = threadIdx.x;
    int rp  = tid >> 5;              // 0..7 row-pair
    int q   = tid & 31;
    int ow4 = q << 2;

    int r0 = slab * 16 + rp * 2;     // first of 2 output rows

    int b    = bt >> 4;
    int trev = bt & 15;
    int t    = 15 - trev;

    const float* xs = x + (size_t)bt * C_ * HW_;
    bool cval = ow4 < (W_ - 4);
    int  co4  = cval ? 4 : 0;

    float acc[RY_][PX_][O_];
    #pragma unroll
    for (int r = 0; r < RY_; ++r)
        #pragma unroll
        for (int p = 0; p < PX_; ++p)
            #pragma unroll
            for (int o = 0; o < O_; ++o) acc[r][p][o] = 0.0f;

    // rows touched: r0-1 .. r0+3; interior slabs 1..6 are select-free
    if (slab >= 1 && slab <= 6) {
        conv_pipeline<false>(xs, Wx, r0, cval, co4, acc, ow4);
    } else {
        conv_pipeline<true>(xs, Wx, r0, cval, co4, acc, ow4);
    }

    float* dstb = xg + (size_t)(t * B_ + b) * O_ * HW_ + r0 * W_ + ow4;
    #pragma unroll
    for (int r = 0; r < RY_; ++r) {
        #pragma unroll
        for (int o = 0; o < O_; ++o) {
            fv4 s;
            s.x = acc[r][0][o]; s.y = acc[r][1][o];
            s.z = acc[r][2][o]; s.w = acc[r][3][o];
            __builtin_nontemporal_store(
                s, reinterpret_cast<fv4*>(dstb + o * HW_ + r * W_));
        }
    }
}

// ---------------- Phase 2: sequential LSTM step ----------------
__global__ __launch_bounds__(256) void step_kernel(
    const float* __restrict__ xg,
    const float* __restrict__ Wh,
    float* __restrict__ out,
    float* __restrict__ cbuf,
    int t)
{
    int gid = blockIdx.x * 256 + threadIdx.x;   // B*HW = 131072
    int b   = gid >> 14;
    int pix = gid & (HW_ - 1);
    int oh  = pix >> 7;
    int ow  = pix & (W_ - 1);

    const float* xgp = xg + (size_t)(t * B_ + b) * O_ * HW_ + pix;
    float acc[O_];
    #pragma unroll
    for (int o = 0; o < O_; ++o)
        acc[o] = __builtin_nontemporal_load(xgp + o * HW_);

    bool cv  = (ow + 1) < W_;
    int  co1 = cv ? 1 : 0;

    if (t > 0) {
        const float* hs = out + (size_t)(b * T_ + (t - 1)) * F_ * HW_;
        #pragma unroll
        for (int kh = 0; kh < KH_; ++kh) {
            int ih  = oh + kh - 1;
            bool rv = (unsigned)ih < (unsigned)H_;
            int ihc = rv ? ih : 0;
            const float* hrow = hs + ihc * W_ + ow;
            const float* wb   = Wh + kh * (KW_ * F_ * O_);
            #pragma unroll
            for (int f = 0; f < F_; ++f) {
                float h0 = hrow[f * HW_];
                float h1 = hrow[f * HW_ + co1];
                h0 = rv ? h0 : 0.0f;
                h1 = (rv && cv) ? h1 : 0.0f;
                #pragma unroll
                for (int o = 0; o < O_; ++o) {
                    acc[o] = fmaf(h0, wb[f * O_ + o], acc[o]);
                    acc[o] = fmaf(h1, wb[F_ * O_ + f * O_ + o], acc[o]);
                }
            }
        }
    }

    size_t cidx = (size_t)b * F_ * HW_ + pix;
    float cp0 = 0.0f, cp1 = 0.0f;
    if (t > 0) { cp0 = cbuf[cidx]; cp1 = cbuf[cidx + HW_]; }

    float gi0 = hsig(acc[0]);
    float gi1 = hsig(acc[1]);
    float gf0 = hsig(acc[2]);
    float gf1 = hsig(acc[3]);
    float gg0 = ftanh(acc[4]);
    float gg1 = ftanh(acc[5]);
    float go0 = hsig(acc[6]);
    float go1 = hsig(acc[7]);

    float cn0 = gf0 * cp0 + gi0 * gg0;
    float cn1 = gf1 * cp1 + gi1 * gg1;
    cbuf[cidx]       = cn0;
    cbuf[cidx + HW_] = cn1;

    size_t oidx = (size_t)(b * T_ + t) * F_ * HW_ + pix;
    out[oidx]       = go0 * ftanh(cn0);
    out[oidx + HW_] = go1 * ftanh(cn1);
}

extern "C" void kernel_launch(void* const* d_in, const int* in_sizes, int n_in,
                              void* d_out, int out_size, void* d_ws, size_t ws_size,
                              hipStream_t stream) {
    const float* x  = (const float*)d_in[0];
    const float* Wx = (const float*)d_in[1];
    const float* Wh = (const float*)d_in[2];
    float* out  = (float*)d_out;

    float* xg   = (float*)d_ws;                                            // 64 MiB
    float* cbuf = (float*)((char*)d_ws + (size_t)64 * 1024 * 1024 + 1024); // 1 MiB

    int xg_blocks = (B_ * T_ * HW_ / (PX_ * RY_)) / 256;   // 1024
    xg_kernel<<<xg_blocks, 256, 0, stream>>>(x, Wx, xg);

    int blocks = (B_ * HW_) / 256;                 // 512
    for (int t = 0; t < T_; ++t) {
        step_kernel<<<blocks, 256, 0, stream>>>(xg, Wh, out, cbuf, t);
    }
}

// Round 8
// 118.947 us; speedup vs baseline: 1.9064x; 1.9064x over previous
//
#include <hip/hip_runtime.h>
#include <cmath>

// ConvLSTM, two-phase:
//   Phase 1: xg = conv_same(x[:, ::-1], Wx), one parallel kernel.
//            Direct global loads (x is L2/L3-resident; LDS staging measured
//            SLOWER, R6; RY=2 pipeline spilled, R7). Thread = 4 px x 8 chans,
//            RY=1. Manual 2-deep register double-buffer over c with NAMED
//            sets (no copies -> no spill). Tail pixel via __shfl_down
//            (halves VMEM instruction count). NT stores for xg.
//   Phase 2: 16 sequential step kernels (h-conv + gates), ~BW-floor.
//
// x:  (B=8, T=16, C=16, H=128, W=128) f32
// Wx: (KH=4, KW=2, C=16, O=8) HWIO     idx = kh*256 + kw*128 + c*8 + o
// Wh: (KH=4, KW=2, F=2, O=8)
// out:(B, T, F=2, H, W) f32
// ws: xg (64 MiB, layout [t][b][o][h][w]) + c-state (1 MiB)

constexpr int B_ = 8;
constexpr int T_ = 16;
constexpr int C_ = 16;
constexpr int F_ = 2;
constexpr int O_ = 8;
constexpr int H_ = 128;
constexpr int W_ = 128;
constexpr int HW_ = H_ * W_;
constexpr int KH_ = 4;
constexpr int KW_ = 2;
constexpr int PX_ = 4;

typedef float fv4 __attribute__((ext_vector_type(4)));

__device__ __forceinline__ float hsig(float z) {
    return fminf(fmaxf(0.2f * z + 0.5f, 0.0f), 1.0f);
}

__device__ __forceinline__ float ftanh(float x) {
    float e = __expf(2.0f * x);
    return fmaf(-2.0f, 1.0f / (e + 1.0f), 1.0f);
}

// load the 4 input rows (ih = r0-1 .. r0+2) of one channel plane
template<bool CHECK>
__device__ __forceinline__ void load4(
    const float* __restrict__ xc,   // channel base + ow4
    int r0m1, fv4 a[KH_])
{
    #pragma unroll
    for (int rr = 0; rr < KH_; ++rr) {
        int ih = r0m1 + rr;
        if (CHECK) {
            bool v = (unsigned)ih < (unsigned)H_;
            a[rr] = *reinterpret_cast<const fv4*>(xc + (v ? ih : 0) * W_);
            if (!v) a[rr] = (fv4)0.0f;
        } else {
            a[rr] = *reinterpret_cast<const fv4*>(xc + ih * W_);
        }
    }
}

// accumulate one channel: 4 kh-taps x 2 kw-taps x 8 outputs x 4 px
__device__ __forceinline__ void accum4(
    const float* __restrict__ wc,   // Wx + c*O_
    const fv4 a[KH_], float acc[PX_][O_], bool cval)
{
    #pragma unroll
    for (int kh = 0; kh < KH_; ++kh) {
        float x4 = __shfl_down(a[kh].x, 1, 64);   // lane q+1's x0 = px ow4+4
        x4 = cval ? x4 : 0.0f;                    // q=31 wrap masked
        const float* wp = wc + kh * (KW_ * C_ * O_);
        #pragma unroll
        for (int o = 0; o < O_; ++o) {
            float w0 = wp[o];              // kw = 0 (uniform -> SGPR)
            float w1 = wp[C_ * O_ + o];    // kw = 1
            acc[0][o] = fmaf(a[kh].x, w0, acc[0][o]);
            acc[1][o] = fmaf(a[kh].y, w0, acc[1][o]);
            acc[2][o] = fmaf(a[kh].z, w0, acc[2][o]);
            acc[3][o] = fmaf(a[kh].w, w0, acc[3][o]);
            acc[0][o] = fmaf(a[kh].y, w1, acc[0][o]);
            acc[1][o] = fmaf(a[kh].z, w1, acc[1][o]);
            acc[2][o] = fmaf(a[kh].w, w1, acc[2][o]);
            acc[3][o] = fmaf(x4,      w1, acc[3][o]);
        }
    }
}

template<bool CHECK>
__device__ __forceinline__ void conv_pipe(
    const float* __restrict__ xb,   // image base + ow4
    const float* __restrict__ Wx,
    int r0m1, bool cval, float acc[PX_][O_])
{
    fv4 A[KH_], Bv[KH_];
    load4<CHECK>(xb, r0m1, A);
    #pragma unroll 1
    for (int cc = 0; cc < C_ - 2; cc += 2) {
        load4<CHECK>(xb + (cc + 1) * HW_, r0m1, Bv);
        accum4(Wx + cc * O_, A, acc, cval);
        load4<CHECK>(xb + (cc + 2) * HW_, r0m1, A);
        accum4(Wx + (cc + 1) * O_, Bv, acc, cval);
    }
    load4<CHECK>(xb + (C_ - 1) * HW_, r0m1, Bv);
    accum4(Wx + (C_ - 2) * O_, A, acc, cval);
    accum4(Wx + (C_ - 1) * O_, Bv, acc, cval);
}

// grid: 2048 blocks x 256 thr; block = 8-row slab of one (b,t) image;
// thread = 4 w-pixels, all 8 gate chans.
__global__ __launch_bounds__(256, 4) void xg_kernel(
    const float* __restrict__ x,
    const float* __restrict__ Wx,
    float* __restrict__ xg)
{
    // XCD-chunked swizzle (2048 % 8 == 0 -> bijective)
    int wid = (blockIdx.x & 7) * 256 + (blockIdx.x >> 3);

    int bt   = wid >> 4;             // 16 blocks per (b,t)
    int slab = wid & 15;

    int tid = threadIdx.x;
    int oh_l = tid >> 5;             // 0..7 local row
    int q    = tid & 31;
    int ow4  = q << 2;

    int r0 = slab * 8 + oh_l;

    int b    = bt >> 4;
    int trev = bt & 15;
    int t    = 15 - trev;

    const float* xb = x + (size_t)bt * C_ * HW_ + ow4;
    bool cval = ow4 < (W_ - 4);

    float acc[PX_][O_];
    #pragma unroll
    for (int p = 0; p < PX_; ++p)
        #pragma unroll
        for (int o = 0; o < O_; ++o) acc[p][o] = 0.0f;

    // rows touched: r0-1 .. r0+2; interior slabs 1..14 are select-free
    if (slab >= 1 && slab <= 14) {
        conv_pipe<false>(xb, Wx, r0 - 1, cval, acc);
    } else {
        conv_pipe<true>(xb, Wx, r0 - 1, cval, acc);
    }

    float* dst = xg + (size_t)(t * B_ + b) * O_ * HW_ + r0 * W_ + ow4;
    #pragma unroll
    for (int o = 0; o < O_; ++o) {
        fv4 s;
        s.x = acc[0][o]; s.y = acc[1][o]; s.z = acc[2][o]; s.w = acc[3][o];
        __builtin_nontemporal_store(s, reinterpret_cast<fv4*>(dst + o * HW_));
    }
}

// ---------------- Phase 2: sequential LSTM step ----------------
__global__ __launch_bounds__(256) void step_kernel(
    const float* __restrict__ xg,
    const float* __restrict__ Wh,
    float* __restrict__ out,
    float* __restrict__ cbuf,
    int t)
{
    int gid = blockIdx.x * 256 + threadIdx.x;   // B*HW = 131072
    int b   = gid >> 14;
    int pix = gid & (HW_ - 1);
    int oh  = pix >> 7;
    int ow  = pix & (W_ - 1);

    const float* xgp = xg + (size_t)(t * B_ + b) * O_ * HW_ + pix;
    float acc[O_];
    #pragma unroll
    for (int o = 0; o < O_; ++o)
        acc[o] = __builtin_nontemporal_load(xgp + o * HW_);

    bool cv  = (ow + 1) < W_;
    int  co1 = cv ? 1 : 0;

    if (t > 0) {
        const float* hs = out + (size_t)(b * T_ + (t - 1)) * F_ * HW_;
        #pragma unroll
        for (int kh = 0; kh < KH_; ++kh) {
            int ih  = oh + kh - 1;
            bool rv = (unsigned)ih < (unsigned)H_;
            int ihc = rv ? ih : 0;
            const float* hrow = hs + ihc * W_ + ow;
            const float* wb   = Wh + kh * (KW_ * F_ * O_);
            #pragma unroll
            for (int f = 0; f < F_; ++f) {
                float h0 = hrow[f * HW_];
                float h1 = hrow[f * HW_ + co1];
                h0 = rv ? h0 : 0.0f;
                h1 = (rv && cv) ? h1 : 0.0f;
                #pragma unroll
                for (int o = 0; o < O_; ++o) {
                    acc[o] = fmaf(h0, wb[f * O_ + o], acc[o]);
                    acc[o] = fmaf(h1, wb[F_ * O_ + f * O_ + o], acc[o]);
                }
            }
        }
    }

    size_t cidx = (size_t)b * F_ * HW_ + pix;
    float cp0 = 0.0f, cp1 = 0.0f;
    if (t > 0) { cp0 = cbuf[cidx]; cp1 = cbuf[cidx + HW_]; }

    float gi0 = hsig(acc[0]);
    float gi1 = hsig(acc[1]);
    float gf0 = hsig(acc[2]);
    float gf1 = hsig(acc[3]);
    float gg0 = ftanh(acc[4]);
    float gg1 = ftanh(acc[5]);
    float go0 = hsig(acc[6]);
    float go1 = hsig(acc[7]);

    float cn0 = gf0 * cp0 + gi0 * gg0;
    float cn1 = gf1 * cp1 + gi1 * gg1;
    cbuf[cidx]       = cn0;
    cbuf[cidx + HW_] = cn1;

    size_t oidx = (size_t)(b * T_ + t) * F_ * HW_ + pix;
    out[oidx]       = go0 * ftanh(cn0);
    out[oidx + HW_] = go1 * ftanh(cn1);
}

extern "C" void kernel_launch(void* const* d_in, const int* in_sizes, int n_in,
                              void* d_out, int out_size, void* d_ws, size_t ws_size,
                              hipStream_t stream) {
    const float* x  = (const float*)d_in[0];
    const float* Wx = (const float*)d_in[1];
    const float* Wh = (const float*)d_in[2];
    float* out  = (float*)d_out;

    float* xg   = (float*)d_ws;                                            // 64 MiB
    float* cbuf = (float*)((char*)d_ws + (size_t)64 * 1024 * 1024 + 1024); // 1 MiB

    int xg_blocks = (B_ * T_ * HW_ / PX_) / 256;   // 2048
    xg_kernel<<<xg_blocks, 256, 0, stream>>>(x, Wx, xg);

    int blocks = (B_ * HW_) / 256;                 // 512
    for (int t = 0; t < T_; ++t) {
        step_kernel<<<blocks, 256, 0, stream>>>(xg, Wh, out, cbuf, t);
    }
}